// Round 1
// baseline (1174.049 us; speedup 1.0000x reference)
//
#include <hip/hip_runtime.h>
#include <math.h>

// ---------------------------------------------------------------------------
// BlockAttnRes: 16 layers of {softmax-mixture over block outputs} -> {LN-MLP}
// B=8, T=8192, D=128. Tokens = 65536. Layer-15 MLP is dead code (skipped).
// Strategy: one fused kernel per layer, 64 tokens/block, 4 waves/block,
// each wave owns 16 tokens end-to-end (attention -> LN -> GEMM1 -> GELU ->
// GEMM2 -> partial accumulate). MFMA bf16 16x16x32, fp32 everywhere else.
// No __syncthreads anywhere: LDS regions are wave-private.
// ---------------------------------------------------------------------------

typedef float    f32x4  __attribute__((ext_vector_type(4)));
typedef __bf16   bf16x8 __attribute__((ext_vector_type(8)));
typedef unsigned short u16x8 __attribute__((ext_vector_type(8)));

#define D   128
#define NT1 16   // GEMM1: N=256 -> 16 n-tiles of 16
#define KK1 4    // GEMM1: K=128 -> 4 k-steps of 32
#define NT2 8    // GEMM2: N=128 -> 8 n-tiles
#define KK2 8    // GEMM2: K=256 -> 8 k-steps

__device__ __forceinline__ unsigned short f2bf(float f) {
  unsigned int u = __builtin_bit_cast(unsigned int, f);
  u += 0x7fffu + ((u >> 16) & 1u);          // round-to-nearest-even
  return (unsigned short)(u >> 16);
}

struct Srcs { const float* p[5]; };

// ---------------------------------------------------------------------------
// Pack W1/W2 (fp32 row-major) into bf16 MFMA B-fragment order:
//   frag idx = ((kk*NT + nt)*64 + lane)*8 + j
//   holds B[k = kk*32 + (lane>>4)*8 + j][n = nt*16 + (lane&15)]
// so a B-fragment is ONE coalesced 16B load per lane at GEMM time.
// ---------------------------------------------------------------------------
__global__ __launch_bounds__(256) void pack_weights(
    const float* __restrict__ W1, const float* __restrict__ W2,
    unsigned short* __restrict__ W1p, unsigned short* __restrict__ W2p)
{
  int t = blockIdx.x * 256 + threadIdx.x;
  if (t < 16 * 128 * 256) {
    int layer = t >> 15, r = t & 32767;
    int j = r & 7, lane = (r >> 3) & 63, nt = (r >> 9) & 15, kk = (r >> 13) & 3;
    int k = kk * 32 + ((lane >> 4) << 3) + j;
    int n = (nt << 4) + (lane & 15);
    W1p[t] = f2bf(W1[(layer << 15) + (k << 8) + n]);     // W1: [128][256]
  } else {
    int t2 = t - 16 * 128 * 256;
    int layer = t2 >> 15, r = t2 & 32767;
    int j = r & 7, lane = (r >> 3) & 63, nt = (r >> 9) & 7, kk = (r >> 12) & 7;
    int k = kk * 32 + ((lane >> 4) << 3) + j;
    int n = (nt << 4) + (lane & 15);
    W2p[t2] = f2bf(W2[(layer << 15) + (k << 7) + n]);    // W2: [256][128]
  }
}

// ---------------------------------------------------------------------------
// Fused per-layer kernel.
//   NSRC  : number of mixture sources (1..5), compile-time so V stays in regs
//   DO_MLP: false only for layer 15 (write h to d_out, skip dead MLP)
//   ACC   : accumulate v into existing partial (layers with l%4 != 0)
// ---------------------------------------------------------------------------
template<int NSRC, bool DO_MLP, bool ACC>
__global__ __launch_bounds__(256)
void layer_kernel(Srcs srcs, const float* __restrict__ wvec,
                  const float* __restrict__ lng, const float* __restrict__ lnb,
                  const unsigned short* __restrict__ W1p, const float* __restrict__ b1,
                  const unsigned short* __restrict__ W2p, const float* __restrict__ b2,
                  float* __restrict__ dst)
{
  // 32 KB LDS. Per-wave 512 u16x8 region; A1 (4x64) aliases the front of
  // A2 (8x64) — safe: A1 is fully consumed into registers before A2 writes,
  // and DS ops of one wave complete in order.
  __shared__ u16x8 smem[2048];

  const int tid  = threadIdx.x;
  const int w    = tid >> 6;          // wave 0..3
  const int l    = tid & 63;          // lane
  const int rloc = (w << 4) + (l >> 2);          // tile-local token row 0..63
  const int tok  = blockIdx.x * 64 + rloc;
  const int c0   = (l & 3) * 32;                 // this lane's 32-col slice

  // ---- attention phase: online softmax over NSRC sources -------------------
  f32x4 wv[8];
  #pragma unroll
  for (int i = 0; i < 8; ++i) wv[i] = *(const f32x4*)(wvec + c0 + i * 4);

  f32x4 hacc[8];
  float m = 0.f, denom = 1.f;
  #pragma unroll
  for (int s = 0; s < NSRC; ++s) {
    const float* vp = srcs.p[s] + (size_t)tok * D + c0;
    f32x4 V[8];
    #pragma unroll
    for (int i = 0; i < 8; ++i) V[i] = *(const f32x4*)(vp + i * 4);
    float s1 = 0.f, s2 = 0.f;
    #pragma unroll
    for (int i = 0; i < 8; ++i) {
      s1 += V[i].x * V[i].x + V[i].y * V[i].y + V[i].z * V[i].z + V[i].w * V[i].w;
      s2 += wv[i].x * V[i].x + wv[i].y * V[i].y + wv[i].z * V[i].z + wv[i].w * V[i].w;
    }
    s1 += __shfl_xor(s1, 1); s1 += __shfl_xor(s1, 2);   // 4-lane token group
    s2 += __shfl_xor(s2, 1); s2 += __shfl_xor(s2, 2);
    float logit = s2 * rsqrtf(s1 * (1.f / 128.f) + 1e-8f);
    if (s == 0) {
      m = logit; denom = 1.f;
      #pragma unroll
      for (int i = 0; i < 8; ++i) hacc[i] = V[i];
    } else {
      float mn = fmaxf(m, logit);
      float sc = __expf(m - mn), e = __expf(logit - mn);
      denom = denom * sc + e;
      #pragma unroll
      for (int i = 0; i < 8; ++i) hacc[i] = hacc[i] * sc + e * V[i];
      m = mn;
    }
  }
  float inv = 1.f / denom;
  #pragma unroll
  for (int i = 0; i < 8; ++i) hacc[i] *= inv;          // hacc = h (f32)

  if (!DO_MLP) {
    float* op = dst + (size_t)tok * D + c0;
    #pragma unroll
    for (int i = 0; i < 8; ++i) *(f32x4*)(op + i * 4) = hacc[i];
    return;
  }

  // ---- LayerNorm (fp32) -> bf16 A-fragments into LDS ----------------------
  float sm = 0.f;
  #pragma unroll
  for (int i = 0; i < 8; ++i) sm += hacc[i].x + hacc[i].y + hacc[i].z + hacc[i].w;
  sm += __shfl_xor(sm, 1); sm += __shfl_xor(sm, 2);
  float mu = sm * (1.f / 128.f);
  float sv = 0.f;
  #pragma unroll
  for (int i = 0; i < 8; ++i) {
    f32x4 d4 = hacc[i] - mu;
    sv += d4.x * d4.x + d4.y * d4.y + d4.z * d4.z + d4.w * d4.w;
  }
  sv += __shfl_xor(sv, 1); sv += __shfl_xor(sv, 2);
  float rs = rsqrtf(sv * (1.f / 128.f) + 1e-5f);

  const int kkw = l & 3;       // this lane's k-step (cols kkw*32..+31)
  const int rw  = l >> 2;      // wave-local row 0..15
  #pragma unroll
  for (int hi = 0; hi < 4; ++hi) {
    f32x4 xa = (hacc[hi * 2 + 0] - mu) * rs;
    f32x4 xb = (hacc[hi * 2 + 1] - mu) * rs;
    f32x4 ga = *(const f32x4*)(lng + c0 + hi * 8);
    f32x4 gb = *(const f32x4*)(lng + c0 + hi * 8 + 4);
    f32x4 ba = *(const f32x4*)(lnb + c0 + hi * 8);
    f32x4 bb = *(const f32x4*)(lnb + c0 + hi * 8 + 4);
    xa = xa * ga + ba;  xb = xb * gb + bb;
    u16x8 pk;
    pk[0] = f2bf(xa.x); pk[1] = f2bf(xa.y); pk[2] = f2bf(xa.z); pk[3] = f2bf(xa.w);
    pk[4] = f2bf(xb.x); pk[5] = f2bf(xb.y); pk[6] = f2bf(xb.z); pk[7] = f2bf(xb.w);
    // A1[kk][lane'] : lane' = hi*16 + row ; holds xn[row][kk*32 + hi*8 + 0..7]
    smem[w * 512 + kkw * 64 + hi * 16 + rw] = pk;
  }

  // ---- GEMM1: [16 x 128] x [128 x 256] ------------------------------------
  bf16x8 a1f[KK1];
  #pragma unroll
  for (int k = 0; k < KK1; ++k)
    a1f[k] = __builtin_bit_cast(bf16x8, smem[w * 512 + k * 64 + l]);

  const u16x8* W1f = (const u16x8*)W1p;
  const f32x4 z4 = {0.f, 0.f, 0.f, 0.f};
  f32x4 acc1[NT1];
  #pragma unroll
  for (int nt = 0; nt < NT1; ++nt) acc1[nt] = z4;
  #pragma unroll
  for (int nt = 0; nt < NT1; ++nt) {
    #pragma unroll
    for (int k = 0; k < KK1; ++k) {
      bf16x8 bfrag = __builtin_bit_cast(bf16x8, W1f[(k * NT1 + nt) * 64 + l]);
      acc1[nt] = __builtin_amdgcn_mfma_f32_16x16x32_bf16(a1f[k], bfrag, acc1[nt], 0, 0, 0);
    }
  }

  // ---- bias + exact GELU -> bf16 A2 fragments into LDS --------------------
  const int ln15 = l & 15, lhi = l >> 4;
  unsigned short* A2u = (unsigned short*)smem;
  #pragma unroll
  for (int nt = 0; nt < NT1; ++nt) {
    float bb1 = b1[nt * 16 + ln15];
    int kk2 = nt >> 1;
    int hi  = ((nt & 1) << 1) + (ln15 >> 3);
    #pragma unroll
    for (int r4 = 0; r4 < 4; ++r4) {
      float x = acc1[nt][r4] + bb1;
      float g = 0.5f * x * (1.f + erff(x * 0.70710678118654752f));
      int lt = hi * 16 + lhi * 4 + r4;                 // target frag-lane
      A2u[(((w * 512 + kk2 * 64 + lt) << 3)) + (l & 7)] = f2bf(g);
    }
  }

  // ---- GEMM2: [16 x 256] x [256 x 128] ------------------------------------
  const u16x8* W2f = (const u16x8*)W2p;
  f32x4 acc2[NT2];
  #pragma unroll
  for (int nt = 0; nt < NT2; ++nt) acc2[nt] = z4;
  #pragma unroll
  for (int k2 = 0; k2 < KK2; ++k2) {
    bf16x8 a2 = __builtin_bit_cast(bf16x8, smem[w * 512 + k2 * 64 + l]);
    #pragma unroll
    for (int nt = 0; nt < NT2; ++nt) {
      bf16x8 bfrag = __builtin_bit_cast(bf16x8, W2f[(k2 * NT2 + nt) * 64 + l]);
      acc2[nt] = __builtin_amdgcn_mfma_f32_16x16x32_bf16(a2, bfrag, acc2[nt], 0, 0, 0);
    }
  }

  // ---- bias + accumulate into partial -------------------------------------
  const int growb = blockIdx.x * 64 + w * 16 + lhi * 4;
  #pragma unroll
  for (int nt = 0; nt < NT2; ++nt) {
    int n = nt * 16 + ln15;
    float bb2 = b2[n];
    #pragma unroll
    for (int r4 = 0; r4 < 4; ++r4) {
      size_t off = (size_t)(growb + r4) * D + n;
      float v = acc2[nt][r4] + bb2;
      if (ACC) v += dst[off];
      dst[off] = v;
    }
  }
}

// ---------------------------------------------------------------------------
extern "C" void kernel_launch(void* const* d_in, const int* in_sizes, int n_in,
                              void* d_out, int out_size, void* d_ws, size_t ws_size,
                              hipStream_t stream)
{
  const float* emb = (const float*)d_in[0];
  const float* w   = (const float*)d_in[1];
  const float* lng = (const float*)d_in[2];
  const float* lnb = (const float*)d_in[3];
  const float* W1  = (const float*)d_in[4];
  const float* b1  = (const float*)d_in[5];
  const float* W2  = (const float*)d_in[6];
  const float* b2  = (const float*)d_in[7];
  float* out = (float*)d_out;

  const int tokens = in_sizes[0] / D;          // 65536
  const size_t tbytes = (size_t)tokens * D * sizeof(float);

  char* wsb = (char*)d_ws;
  float* P[4];
  for (int i = 0; i < 4; ++i) P[i] = (float*)(wsb + (size_t)i * tbytes);
  unsigned short* W1p = (unsigned short*)(wsb + 4 * tbytes);
  unsigned short* W2p = W1p + 16 * 128 * 256;

  pack_weights<<<(16 * 128 * 256 * 2) / 256, 256, 0, stream>>>(W1, W2, W1p, W2p);

  const int grid = tokens / 64;
  for (int lyr = 0; lyr < 16; ++lyr) {
    int  b    = lyr >> 2;
    bool hasP = (lyr & 3) != 0;
    int  nsrc = 1 + b + (hasP ? 1 : 0);

    Srcs S{};
    S.p[0] = emb;
    for (int i = 0; i < b; ++i) S.p[1 + i] = P[i];
    if (hasP) S.p[1 + b] = P[b];

    float* dst = (lyr == 15) ? out : P[b];
    const float* wl  = w   + lyr * D;
    const float* gl  = lng + lyr * D;
    const float* bl  = lnb + lyr * D;
    const unsigned short* W1l = W1p + lyr * 32768;
    const float* b1l = b1  + lyr * 256;
    const unsigned short* W2l = W2p + lyr * 32768;
    const float* b2l = b2  + lyr * D;

#define LAUNCH(NS, MLP, AC) \
    layer_kernel<NS, MLP, AC><<<grid, 256, 0, stream>>>(S, wl, gl, bl, W1l, b1l, W2l, b2l, dst)

    if (lyr == 15) {
      LAUNCH(5, false, false);          // final mixture -> d_out, MLP dead
    } else if (!hasP) {
      if      (nsrc == 1) LAUNCH(1, true, false);
      else if (nsrc == 2) LAUNCH(2, true, false);
      else if (nsrc == 3) LAUNCH(3, true, false);
      else                LAUNCH(4, true, false);
    } else {
      if      (nsrc == 2) LAUNCH(2, true, true);
      else if (nsrc == 3) LAUNCH(3, true, true);
      else if (nsrc == 4) LAUNCH(4, true, true);
      else                LAUNCH(5, true, true);
    }
#undef LAUNCH
  }
}